// Round 1
// baseline (9292.017 us; speedup 1.0000x reference)
//
#include <hip/hip_runtime.h>
#include <math.h>

#define TWO_PI_F 6.28318530717958647692f

// Problem constants
// x: [32,56,56,384], med=768, nb=8, bs=96, Wf=29
#define MROWS 100352      // 32*56*56
#define CIN   384
#define MED   768
#define NBLK  8
#define BSZ   96
#define HH    56
#define WWI   56
#define WF    29
#define ROWS2 1792        // 32*56

// ws layout (float offsets)
#define OFF_MID  0
#define SZ_MID   ((size_t)MROWS * MED)                  // 77,070,336
#define OFF_XWR  (OFF_MID + SZ_MID)
#define SZ_XW    ((size_t)ROWS2 * WF * BSZ)             // 4,988,928
#define OFF_XWI  (OFF_XWR + SZ_XW)
#define OFF_CWF  (OFF_XWI + SZ_XW)
#define SZ_CWF   ((size_t)WF * WWI * 2)                 // 3,248
#define OFF_HT   (OFF_CWF + SZ_CWF)
#define SZ_HT    ((size_t)HH * HH * 2)                  // 6,272
#define OFF_IWT  (OFF_HT + SZ_HT)
#define SZ_IWT   ((size_t)WWI * WF * 2)                 // 3,248
#define WS_FLOATS (OFF_IWT + SZ_IWT)

static __device__ __forceinline__ float softshrink01(float v){
    float t = fabsf(v) - 0.01f;
    return (t > 0.f) ? copysignf(t, v) : 0.f;
}

// ---------------- twiddle tables ----------------
__global__ __launch_bounds__(256) void init_tables_kernel(
        float* __restrict__ cwF, float* __restrict__ hT, float* __restrict__ iwT)
{
    int tid = threadIdx.x;
    // forward rfft along W: Xw[f] = (1/56) sum_w h[w] e^{-2pi i f w/56}
    for (int idx = tid; idx < WF * WWI; idx += 256){
        int f = idx / WWI, w = idx % WWI;
        float ang = TWO_PI_F * (float)((f * w) % WWI) / (float)WWI;
        cwF[2*idx]   =  cosf(ang) * (1.f / 56.f);
        cwF[2*idx+1] = -sinf(ang) * (1.f / 56.f);
    }
    // fft along H (both directions use symmetry k*h): (cos, sin)
    for (int idx = tid; idx < HH * HH; idx += 256){
        int k = idx / HH, h = idx % HH;
        float ang = TWO_PI_F * (float)((k * h) % HH) / (float)HH;
        hT[2*idx]   = cosf(ang);
        hT[2*idx+1] = sinf(ang);
    }
    // inverse rfft along W: out[w] = sum_f alpha_f/56 * (Yr cos - Yi sin)
    for (int idx = tid; idx < WWI * WF; idx += 256){
        int w = idx / WF, f = idx % WF;
        float ang = TWO_PI_F * (float)((f * w) % WWI) / (float)WWI;
        float alpha = (f == 0 || f == WF - 1) ? 1.f : 2.f;
        iwT[2*idx]   =  alpha * cosf(ang) * (1.f / 56.f);
        iwT[2*idx+1] = -alpha * sinf(ang) * (1.f / 56.f);
    }
}

// ---------------- fp32 GEMM, 128x128 tile, BK=16, 256 threads ----------------
// C[M,N] = A[M,K] * B[K,N]; optional StarReLU epilogue (s*relu(v)^2 + b)
template<bool STAR>
__global__ __launch_bounds__(256) void gemm_kernel(
        const float* __restrict__ A, const float* __restrict__ B,
        float* __restrict__ C, int Kdim, int Ndim,
        const float* __restrict__ sptr, const float* __restrict__ bptr)
{
    __shared__ float As[16][132];   // [k][m], padded to kill write conflicts
    __shared__ float Bs[16][128];   // [k][n]
    const int tid = threadIdx.x;
    const int tx = tid & 15, ty = tid >> 4;
    const int bm = blockIdx.x, bn = blockIdx.y;

    float acc[8][8];
    #pragma unroll
    for (int i = 0; i < 8; ++i)
        #pragma unroll
        for (int j = 0; j < 8; ++j) acc[i][j] = 0.f;

    const float* Aptr = A + (size_t)bm * 128 * Kdim;
    const float* Bptr = B + (size_t)bn * 128;

    for (int k0 = 0; k0 < Kdim; k0 += 16){
        // A tile: 128 rows x 16 k
        #pragma unroll
        for (int j = 0; j < 2; ++j){
            int m  = (tid >> 2) + j * 64;
            int kc = (tid & 3) * 4;
            const float4 va = *(const float4*)(Aptr + (size_t)m * Kdim + k0 + kc);
            As[kc+0][m] = va.x; As[kc+1][m] = va.y;
            As[kc+2][m] = va.z; As[kc+3][m] = va.w;
        }
        // B tile: 16 k x 128 n
        #pragma unroll
        for (int j = 0; j < 2; ++j){
            int kr = (tid >> 5) + j * 8;
            int nc = (tid & 31) * 4;
            *(float4*)(&Bs[kr][nc]) = *(const float4*)(Bptr + (size_t)(k0 + kr) * Ndim + nc);
        }
        __syncthreads();
        #pragma unroll
        for (int k = 0; k < 16; ++k){
            float a[8], b[8];
            *(float4*)(a)   = *(const float4*)(&As[k][ty*4]);
            *(float4*)(a+4) = *(const float4*)(&As[k][64 + ty*4]);
            *(float4*)(b)   = *(const float4*)(&Bs[k][tx*4]);
            *(float4*)(b+4) = *(const float4*)(&Bs[k][64 + tx*4]);
            #pragma unroll
            for (int i = 0; i < 8; ++i)
                #pragma unroll
                for (int j = 0; j < 8; ++j)
                    acc[i][j] = fmaf(a[i], b[j], acc[i][j]);
        }
        __syncthreads();
    }

    float s = 0.f, bb = 0.f;
    if (STAR){ s = sptr[0]; bb = bptr[0]; }
    #pragma unroll
    for (int i = 0; i < 8; ++i){
        int m = bm * 128 + ((i < 4) ? (ty*4 + i) : (64 + ty*4 + (i - 4)));
        #pragma unroll
        for (int jj = 0; jj < 2; ++jj){
            int n = bn * 128 + ((jj == 0) ? (tx*4) : (64 + tx*4));
            float4 v;
            v.x = acc[i][jj*4+0]; v.y = acc[i][jj*4+1];
            v.z = acc[i][jj*4+2]; v.w = acc[i][jj*4+3];
            if (STAR){
                float r;
                r = fmaxf(v.x, 0.f); v.x = fmaf(s*r, r, bb);
                r = fmaxf(v.y, 0.f); v.y = fmaf(s*r, r, bb);
                r = fmaxf(v.z, 0.f); v.z = fmaf(s*r, r, bb);
                r = fmaxf(v.w, 0.f); v.w = fmaf(s*r, r, bb);
            }
            *(float4*)(&C[(size_t)m * Ndim + n]) = v;
        }
    }
}

// ---------------- forward rfft along W (one channel-block) ----------------
// grid = 1792 (one per (b, i-row)); mid[row2][w][m] -> XwR/XwI[row2][f][c]
__global__ __launch_bounds__(256) void fftW_kernel(
        const float* __restrict__ mid, float* __restrict__ XwR, float* __restrict__ XwI,
        const float* __restrict__ cwF, int blk)
{
    __shared__ float T[WWI * BSZ];          // [w][c]  21.5 KB
    const int row2 = blockIdx.x;
    const float* src = mid + (size_t)row2 * WWI * MED + blk * BSZ;
    for (int idx = threadIdx.x; idx < WWI * BSZ; idx += 256){
        int w = idx / BSZ, c = idx - w * BSZ;
        T[idx] = src[(size_t)w * MED + c];
    }
    __syncthreads();
    float* dstR = XwR + (size_t)row2 * WF * BSZ;
    float* dstI = XwI + (size_t)row2 * WF * BSZ;
    const float2* tw2 = (const float2*)cwF;
    for (int idx = threadIdx.x; idx < WF * BSZ; idx += 256){
        int f = idx / BSZ, c = idx - f * BSZ;
        const float2* tw = tw2 + f * WWI;
        float re = 0.f, im = 0.f;
        #pragma unroll 8
        for (int w = 0; w < WWI; ++w){
            float v = T[w * BSZ + c];
            float2 t = tw[w];
            re = fmaf(v, t.x, re);
            im = fmaf(v, t.y, im);
        }
        dstR[idx] = re;
        dstI[idx] = im;
    }
}

// ---------------- fused: fft-H, MLP(2 layers)+softshrink, ifft-H ----------------
// grid = 32*29 = 928 (one per (b, f)); in-place on XwR/XwI tile [56 x 96]
// dynamic LDS: bufA(5376 f2) + bufB(5376 f2) + wbuf(4608 f2) = 122,880 B
__global__ __launch_bounds__(256) void fusedH_kernel(
        float* __restrict__ XwR, float* __restrict__ XwI,
        const float* __restrict__ w1, const float* __restrict__ b1,
        const float* __restrict__ w2, const float* __restrict__ b2,
        const float* __restrict__ hT, int blk)
{
    extern __shared__ float2 sm2[];
    float2* bufA = sm2;              // 5376
    float2* bufB = sm2 + 5376;       // 5376
    float2* wbuf = sm2 + 10752;      // 4608 (96 x 48, (W0,W1) pairs)
    const int tid = threadIdx.x;
    const int b = blockIdx.x / WF, f = blockIdx.x - b * WF;
    float* R = XwR + ((size_t)b * HH * WF + f) * BSZ;
    float* I = XwI + ((size_t)b * HH * WF + f) * BSZ;
    const float2* hTf = (const float2*)hT;
    const int HSTRIDE = WF * BSZ;    // 2784

    // load tile (h x c)
    for (int idx = tid; idx < HH * BSZ; idx += 256){
        int h = idx / BSZ, c = idx - h * BSZ;
        bufA[idx] = make_float2(R[(size_t)h * HSTRIDE + c], I[(size_t)h * HSTRIDE + c]);
    }
    __syncthreads();

    // forward DFT along H: bufB[k][c] = sum_h bufA[h][c] * e^{-2pi i k h/56}
    for (int idx = tid; idx < HH * BSZ; idx += 256){
        int k = idx / BSZ, c = idx - k * BSZ;
        const float2* tw = hTf + k * HH;
        float re = 0.f, im = 0.f;
        #pragma unroll 8
        for (int h = 0; h < HH; ++h){
            float2 t = bufA[h * BSZ + c];
            float2 w = tw[h];
            re += t.x * w.x + t.y * w.y;
            im += t.y * w.x - t.x * w.y;
        }
        bufB[idx] = make_float2(re, im);
    }

    // ---- layer 1 (ReLU): read bufB -> write bufA ----
    const float* W10 = w1 + (size_t)blk * BSZ * BSZ;
    const float* W11 = w1 + (size_t)(NBLK + blk) * BSZ * BSZ;
    const float* B10 = b1 + blk * BSZ;
    const float* B11 = b1 + (NBLK + blk) * BSZ;
    #pragma unroll 1
    for (int half = 0; half < 2; ++half){
        const int base = half * 48;
        __syncthreads();
        for (int idx = tid; idx < BSZ * 48; idx += 256){
            int i = idx / 48, oo = idx - i * 48;
            wbuf[idx] = make_float2(W10[i * BSZ + base + oo], W11[i * BSZ + base + oo]);
        }
        __syncthreads();
        for (int t = tid; t < HH * 24; t += 256){
            int row = t / 24, oo = t - row * 24;
            int o = base + oo;
            float2 a0 = make_float2(B10[o],      B11[o]);
            float2 a1 = make_float2(B10[o + 24], B11[o + 24]);
            const float2* xr = bufB + row * BSZ;
            #pragma unroll 8
            for (int i = 0; i < BSZ; ++i){
                float2 x  = xr[i];
                float2 wa = wbuf[i * 48 + oo];
                float2 wb = wbuf[i * 48 + oo + 24];
                a0.x += x.x * wa.x - x.y * wa.y;
                a0.y += x.y * wa.x + x.x * wa.y;
                a1.x += x.x * wb.x - x.y * wb.y;
                a1.y += x.y * wb.x + x.x * wb.y;
            }
            bufA[row * BSZ + o]      = make_float2(fmaxf(a0.x, 0.f), fmaxf(a0.y, 0.f));
            bufA[row * BSZ + o + 24] = make_float2(fmaxf(a1.x, 0.f), fmaxf(a1.y, 0.f));
        }
    }

    // ---- layer 2 + softshrink: read bufA -> write bufB ----
    const float* W20 = w2 + (size_t)blk * BSZ * BSZ;
    const float* W21 = w2 + (size_t)(NBLK + blk) * BSZ * BSZ;
    const float* B20 = b2 + blk * BSZ;
    const float* B21 = b2 + (NBLK + blk) * BSZ;
    #pragma unroll 1
    for (int half = 0; half < 2; ++half){
        const int base = half * 48;
        __syncthreads();
        for (int idx = tid; idx < BSZ * 48; idx += 256){
            int i = idx / 48, oo = idx - i * 48;
            wbuf[idx] = make_float2(W20[i * BSZ + base + oo], W21[i * BSZ + base + oo]);
        }
        __syncthreads();
        for (int t = tid; t < HH * 24; t += 256){
            int row = t / 24, oo = t - row * 24;
            int o = base + oo;
            float2 a0 = make_float2(B20[o],      B21[o]);
            float2 a1 = make_float2(B20[o + 24], B21[o + 24]);
            const float2* xr = bufA + row * BSZ;
            #pragma unroll 8
            for (int i = 0; i < BSZ; ++i){
                float2 x  = xr[i];
                float2 wa = wbuf[i * 48 + oo];
                float2 wb = wbuf[i * 48 + oo + 24];
                a0.x += x.x * wa.x - x.y * wa.y;
                a0.y += x.y * wa.x + x.x * wa.y;
                a1.x += x.x * wb.x - x.y * wb.y;
                a1.y += x.y * wb.x + x.x * wb.y;
            }
            bufB[row * BSZ + o]      = make_float2(softshrink01(a0.x), softshrink01(a0.y));
            bufB[row * BSZ + o + 24] = make_float2(softshrink01(a1.x), softshrink01(a1.y));
        }
    }
    __syncthreads();

    // inverse DFT along H: out[h][c] = sum_k bufB[k][c] * e^{+2pi i k h/56}
    for (int idx = tid; idx < HH * BSZ; idx += 256){
        int h = idx / BSZ, c = idx - h * BSZ;
        const float2* tw = hTf + h * HH;   // symmetric in (k,h)
        float re = 0.f, im = 0.f;
        #pragma unroll 8
        for (int k = 0; k < HH; ++k){
            float2 t = bufB[k * BSZ + c];
            float2 w = tw[k];
            re += t.x * w.x - t.y * w.y;
            im += t.x * w.y + t.y * w.x;
        }
        R[(size_t)h * HSTRIDE + c] = re;
        I[(size_t)h * HSTRIDE + c] = im;
    }
}

// ---------------- inverse rfft along W + skip-add (one channel-block) ----------------
// grid = 1792; XwR/XwI[row2][f][c] -> mid[row2][w][blk*96+c] += (skip already there)
__global__ __launch_bounds__(256) void ifftW_kernel(
        const float* __restrict__ XwR, const float* __restrict__ XwI,
        float* __restrict__ mid, const float* __restrict__ iwT, int blk)
{
    __shared__ float TR[WF * BSZ];   // 10.9 KB
    __shared__ float TI[WF * BSZ];
    const int row2 = blockIdx.x;
    const float* srcR = XwR + (size_t)row2 * WF * BSZ;
    const float* srcI = XwI + (size_t)row2 * WF * BSZ;
    for (int idx = threadIdx.x; idx < WF * BSZ; idx += 256){
        TR[idx] = srcR[idx];
        TI[idx] = srcI[idx];
    }
    __syncthreads();
    float* dst = mid + (size_t)row2 * WWI * MED + blk * BSZ;
    const float2* tw2 = (const float2*)iwT;
    for (int idx = threadIdx.x; idx < WWI * BSZ; idx += 256){
        int w = idx / BSZ, c = idx - w * BSZ;
        const float2* t = tw2 + w * WF;
        float acc = 0.f;
        #pragma unroll 8
        for (int fq = 0; fq < WF; ++fq){
            float2 a = t[fq];
            acc = fmaf(TR[fq * BSZ + c], a.x, acc);
            acc = fmaf(TI[fq * BSZ + c], a.y, acc);
        }
        float* p = dst + (size_t)w * MED + c;
        *p = acc + *p;   // += skip (h) already resident in mid
    }
}

// ---------------- launcher ----------------
extern "C" void kernel_launch(void* const* d_in, const int* in_sizes, int n_in,
                              void* d_out, int out_size, void* d_ws, size_t ws_size,
                              hipStream_t stream)
{
    (void)in_sizes; (void)n_in; (void)out_size;
    const float* x      = (const float*)d_in[0];
    const float* w_pw1  = (const float*)d_in[1];
    const float* sscale = (const float*)d_in[2];
    const float* sbias  = (const float*)d_in[3];
    const float* w1     = (const float*)d_in[4];
    const float* b1     = (const float*)d_in[5];
    const float* w2     = (const float*)d_in[6];
    const float* b2     = (const float*)d_in[7];
    const float* w_pw2  = (const float*)d_in[8];
    float* out = (float*)d_out;
    float* ws  = (float*)d_ws;

    if (ws_size < WS_FLOATS * sizeof(float)) return;  // insufficient scratch

    float* mid = ws + OFF_MID;
    float* XwR = ws + OFF_XWR;
    float* XwI = ws + OFF_XWI;
    float* cwF = ws + OFF_CWF;
    float* hT  = ws + OFF_HT;
    float* iwT = ws + OFF_IWT;

    init_tables_kernel<<<1, 256, 0, stream>>>(cwF, hT, iwT);

    // pwconv1 + StarReLU: mid = s*relu(x@w_pw1)^2 + b
    gemm_kernel<true><<<dim3(MROWS / 128, MED / 128), 256, 0, stream>>>(
        x, w_pw1, mid, CIN, MED, sscale, sbias);

    // spectral path, one channel-block (96 ch) at a time
    for (int blk = 0; blk < NBLK; ++blk){
        fftW_kernel<<<ROWS2, 256, 0, stream>>>(mid, XwR, XwI, cwF, blk);
        fusedH_kernel<<<32 * WF, 256, 122880, stream>>>(XwR, XwI, w1, b1, w2, b2, hT, blk);
        ifftW_kernel<<<ROWS2, 256, 0, stream>>>(XwR, XwI, mid, iwT, blk);
    }

    // pwconv2: out = mid @ w_pw2
    gemm_kernel<false><<<dim3(MROWS / 128, CIN / 128), 256, 0, stream>>>(
        mid, w_pw2, out, MED, CIN, nullptr, nullptr);
}

// Round 2
// 4952.688 us; speedup vs baseline: 1.8762x; 1.8762x over previous
//
#include <hip/hip_runtime.h>
#include <math.h>

#define TWO_PI_F 6.28318530717958647692f

// Problem constants: x [32,56,56,384], med=768, nb=8, bs=96, Wf=29
#define MROWS 100352      // 32*56*56
#define CIN   384
#define MED   768
#define NBLK  8
#define BSZ   96
#define HH    56
#define WWI   56
#define WF    29
#define ROWS2 1792        // 32*56
#define NPOS  51968       // ROWS2*WF
#define NROW  2784        // WF*BSZ (floats per (b,h) spectral row)

#define SZ_XW ((size_t)ROWS2 * WF * BSZ)   // 4,988,928 floats per plane per slot

// ---- ws layout (float offsets): tables | mid | A(R,I) | B(R,I) ----
#define OFF_CWF 0
#define SZ_CWF  (WF*WWI*2)                  // 3248
#define OFF_HTF (OFF_CWF + SZ_CWF)
#define SZ_HT   (HH*HH*2)                   // 6272
#define OFF_HTI (OFF_HTF + SZ_HT)
#define OFF_IWT (OFF_HTI + SZ_HT)
#define SZ_IWT  (WWI*WF*2)                  // 3248
#define OFF_MID ((size_t)(OFF_IWT + SZ_IWT))   // 19040
#define SZ_MID  ((size_t)MROWS * MED)
#define OFF_BUF (OFF_MID + SZ_MID)

static __device__ __forceinline__ float softshrink01(float v){
    float t = fabsf(v) - 0.01f;
    return (t > 0.f) ? copysignf(t, v) : 0.f;
}

// ---------------- twiddle tables ----------------
__global__ __launch_bounds__(256) void init_tables_kernel(
        float* __restrict__ cwF, float* __restrict__ hTf,
        float* __restrict__ hTi, float* __restrict__ iwT)
{
    int tid = threadIdx.x;
    // forward rfft along W: (1/56) e^{-2pi i f w/56}
    for (int idx = tid; idx < WF * WWI; idx += 256){
        int f = idx / WWI, w = idx % WWI;
        float ang = TWO_PI_F * (float)((f * w) % WWI) / (float)WWI;
        cwF[2*idx]   =  cosf(ang) * (1.f / 56.f);
        cwF[2*idx+1] = -sinf(ang) * (1.f / 56.f);
    }
    // H-DFT tables: fwd (cos, -sin), inv (cos, +sin); unscaled
    for (int idx = tid; idx < HH * HH; idx += 256){
        int k = idx / HH, h = idx % HH;
        float ang = TWO_PI_F * (float)((k * h) % HH) / (float)HH;
        float c = cosf(ang), s = sinf(ang);
        hTf[2*idx]   = c;  hTf[2*idx+1] = -s;
        hTi[2*idx]   = c;  hTi[2*idx+1] =  s;
    }
    // inverse rfft along W (alpha-folded, 1/56 scaled)
    for (int idx = tid; idx < WWI * WF; idx += 256){
        int w = idx / WF, f = idx % WF;
        float ang = TWO_PI_F * (float)((f * w) % WWI) / (float)WWI;
        float alpha = (f == 0 || f == WF - 1) ? 1.f : 2.f;
        iwT[2*idx]   =  alpha * cosf(ang) * (1.f / 56.f);
        iwT[2*idx+1] = -alpha * sinf(ang) * (1.f / 56.f);
    }
}

// ---------------- fp32 GEMM, 128x128 tile, BK=16, 256 threads ----------------
template<bool STAR>
__global__ __launch_bounds__(256) void gemm_kernel(
        const float* __restrict__ A, const float* __restrict__ B,
        float* __restrict__ C, int Kdim, int Ndim,
        const float* __restrict__ sptr, const float* __restrict__ bptr)
{
    __shared__ float As[16][132];
    __shared__ float Bs[16][128];
    const int tid = threadIdx.x;
    const int tx = tid & 15, ty = tid >> 4;
    const int bm = blockIdx.x, bn = blockIdx.y;

    float acc[8][8];
    #pragma unroll
    for (int i = 0; i < 8; ++i)
        #pragma unroll
        for (int j = 0; j < 8; ++j) acc[i][j] = 0.f;

    const float* Aptr = A + (size_t)bm * 128 * Kdim;
    const float* Bptr = B + (size_t)bn * 128;

    for (int k0 = 0; k0 < Kdim; k0 += 16){
        #pragma unroll
        for (int j = 0; j < 2; ++j){
            int m  = (tid >> 2) + j * 64;
            int kc = (tid & 3) * 4;
            const float4 va = *(const float4*)(Aptr + (size_t)m * Kdim + k0 + kc);
            As[kc+0][m] = va.x; As[kc+1][m] = va.y;
            As[kc+2][m] = va.z; As[kc+3][m] = va.w;
        }
        #pragma unroll
        for (int j = 0; j < 2; ++j){
            int kr = (tid >> 5) + j * 8;
            int nc = (tid & 31) * 4;
            *(float4*)(&Bs[kr][nc]) = *(const float4*)(Bptr + (size_t)(k0 + kr) * Ndim + nc);
        }
        __syncthreads();
        #pragma unroll
        for (int k = 0; k < 16; ++k){
            float a[8], b[8];
            *(float4*)(a)   = *(const float4*)(&As[k][ty*4]);
            *(float4*)(a+4) = *(const float4*)(&As[k][64 + ty*4]);
            *(float4*)(b)   = *(const float4*)(&Bs[k][tx*4]);
            *(float4*)(b+4) = *(const float4*)(&Bs[k][64 + tx*4]);
            #pragma unroll
            for (int i = 0; i < 8; ++i)
                #pragma unroll
                for (int j = 0; j < 8; ++j)
                    acc[i][j] = fmaf(a[i], b[j], acc[i][j]);
        }
        __syncthreads();
    }

    float s = 0.f, bb = 0.f;
    if (STAR){ s = sptr[0]; bb = bptr[0]; }
    #pragma unroll
    for (int i = 0; i < 8; ++i){
        int m = bm * 128 + ((i < 4) ? (ty*4 + i) : (64 + ty*4 + (i - 4)));
        #pragma unroll
        for (int jj = 0; jj < 2; ++jj){
            int n = bn * 128 + ((jj == 0) ? (tx*4) : (64 + tx*4));
            float4 v;
            v.x = acc[i][jj*4+0]; v.y = acc[i][jj*4+1];
            v.z = acc[i][jj*4+2]; v.w = acc[i][jj*4+3];
            if (STAR){
                float r;
                r = fmaxf(v.x, 0.f); v.x = fmaf(s*r, r, bb);
                r = fmaxf(v.y, 0.f); v.y = fmaf(s*r, r, bb);
                r = fmaxf(v.z, 0.f); v.z = fmaf(s*r, r, bb);
                r = fmaxf(v.w, 0.f); v.w = fmaf(s*r, r, bb);
            }
            *(float4*)(&C[(size_t)m * Ndim + n]) = v;
        }
    }
}

// ---------------- forward rfft along W ----------------
// grid (1792, NY); blk = blk0 + blockIdx.y, slot = blockIdx.y
__global__ __launch_bounds__(256) void fftW_kernel(
        const float* __restrict__ mid, float* __restrict__ AR, float* __restrict__ AI,
        const float* __restrict__ cwF, int blk0)
{
    __shared__ float T[WWI * BSZ];          // 21.5 KB
    const int slot = blockIdx.y;
    const int blk = blk0 + slot;
    const int row2 = blockIdx.x;
    const float* src = mid + (size_t)row2 * WWI * MED + blk * BSZ;
    for (int idx = threadIdx.x; idx < WWI * BSZ; idx += 256){
        int w = idx / BSZ, c = idx - w * BSZ;
        T[idx] = src[(size_t)w * MED + c];
    }
    __syncthreads();
    float* dstR = AR + (size_t)slot * SZ_XW + (size_t)row2 * WF * BSZ;
    float* dstI = AI + (size_t)slot * SZ_XW + (size_t)row2 * WF * BSZ;
    const float2* tw2 = (const float2*)cwF;
    for (int idx = threadIdx.x; idx < WF * BSZ; idx += 256){
        int f = idx / BSZ, c = idx - f * BSZ;
        const float2* tw = tw2 + f * WWI;
        float re = 0.f, im = 0.f;
        #pragma unroll 8
        for (int w = 0; w < WWI; ++w){
            float v = T[w * BSZ + c];
            float2 t = tw[w];
            re = fmaf(v, t.x, re);
            im = fmaf(v, t.y, im);
        }
        dstR[idx] = re;
        dstI[idx] = im;
    }
}

// ---------------- complex DFT along H as register-tiled GEMM ----------------
// out[k,n] = sum_h tw[k,h] * in[h,n]   (complex; tw sign pre-baked)
// grid.x = 32*58 (b, n-tile of 48); grid.y = NY (slot). 256 thr, 224 compute.
__global__ __launch_bounds__(256) void cgemmH_kernel(
        const float* __restrict__ inR, const float* __restrict__ inI,
        float* __restrict__ outR, float* __restrict__ outI,
        const float* __restrict__ twg)
{
    __shared__ float2 twS[HH * HH];     // 25.1 KB
    __shared__ float2 bS[HH * 48];      // 21.5 KB
    const int slot = blockIdx.y;
    const int b  = blockIdx.x / 58;
    const int n0 = (blockIdx.x - b * 58) * 48;
    const int tid = threadIdx.x;
    const size_t base = (size_t)slot * SZ_XW + (size_t)b * HH * NROW;
    const float* iR = inR + base;
    const float* iI = inI + base;

    const float2* twg2 = (const float2*)twg;
    for (int i = tid; i < HH * HH; i += 256) twS[i] = twg2[i];
    for (int i = tid; i < HH * 48; i += 256){
        int h = i / 48, n = i - h * 48;
        bS[i] = make_float2(iR[(size_t)h * NROW + n0 + n], iI[(size_t)h * NROW + n0 + n]);
    }
    __syncthreads();

    const int ng = tid & 15, kg = tid >> 4;
    if (kg < 14){
        float2 acc[4][3];
        #pragma unroll
        for (int j = 0; j < 4; ++j)
            #pragma unroll
            for (int t = 0; t < 3; ++t) acc[j][t] = make_float2(0.f, 0.f);

        for (int h = 0; h < HH; ++h){
            float2 x0 = bS[h * 48 + ng * 3 + 0];
            float2 x1 = bS[h * 48 + ng * 3 + 1];
            float2 x2 = bS[h * 48 + ng * 3 + 2];
            #pragma unroll
            for (int j = 0; j < 4; ++j){
                float2 w = twS[(kg * 4 + j) * HH + h];
                acc[j][0].x = fmaf(x0.x, w.x, fmaf(-x0.y, w.y, acc[j][0].x));
                acc[j][0].y = fmaf(x0.y, w.x, fmaf( x0.x, w.y, acc[j][0].y));
                acc[j][1].x = fmaf(x1.x, w.x, fmaf(-x1.y, w.y, acc[j][1].x));
                acc[j][1].y = fmaf(x1.y, w.x, fmaf( x1.x, w.y, acc[j][1].y));
                acc[j][2].x = fmaf(x2.x, w.x, fmaf(-x2.y, w.y, acc[j][2].x));
                acc[j][2].y = fmaf(x2.y, w.x, fmaf( x2.x, w.y, acc[j][2].y));
            }
        }
        float* oR = outR + base;
        float* oI = outI + base;
        #pragma unroll
        for (int j = 0; j < 4; ++j){
            int k = kg * 4 + j;
            #pragma unroll
            for (int t = 0; t < 3; ++t){
                int n = n0 + ng * 3 + t;
                oR[(size_t)k * NROW + n] = acc[j][t].x;
                oI[(size_t)k * NROW + n] = acc[j][t].y;
            }
        }
    }
}

// ---------------- block-diagonal complex MLP layer ----------------
// ACT: 1 = ReLU (layer1), 2 = softshrink (layer2)
// grid.x = NPOS/64 = 812; grid.y = NY. 256 thr, 4m x 6o register tile, K-chunks of 24.
template<int ACT>
__global__ __launch_bounds__(256) void cmlp_kernel(
        const float* __restrict__ inR, const float* __restrict__ inI,
        float* __restrict__ outR, float* __restrict__ outI,
        const float* __restrict__ w, const float* __restrict__ bias, int blk0)
{
    __shared__ float2 xS[64 * 24];   // 12.3 KB
    __shared__ float2 wS[24 * 96];   // 18.4 KB
    const int slot = blockIdx.y;
    const int blk = blk0 + slot;
    const int m0 = blockIdx.x * 64;
    const int tid = threadIdx.x;
    const float* W0 = w + (size_t)blk * BSZ * BSZ;
    const float* W1 = w + (size_t)(NBLK + blk) * BSZ * BSZ;
    const size_t base = (size_t)slot * SZ_XW + (size_t)m0 * BSZ;
    const float* iR = inR + base;
    const float* iI = inI + base;
    const int og = tid & 15, mg = tid >> 4;

    float2 acc[4][6];
    #pragma unroll
    for (int j = 0; j < 4; ++j)
        #pragma unroll
        for (int t = 0; t < 6; ++t) acc[j][t] = make_float2(0.f, 0.f);

    for (int i0 = 0; i0 < BSZ; i0 += 24){
        __syncthreads();
        for (int idx = tid; idx < 64 * 24; idx += 256){
            int m = idx / 24, ii = idx - m * 24;
            xS[idx] = make_float2(iR[(size_t)m * BSZ + i0 + ii], iI[(size_t)m * BSZ + i0 + ii]);
        }
        for (int idx = tid; idx < 24 * 96; idx += 256){
            int ii = idx / 96, o = idx - ii * 96;
            wS[idx] = make_float2(W0[(size_t)(i0 + ii) * BSZ + o], W1[(size_t)(i0 + ii) * BSZ + o]);
        }
        __syncthreads();
        for (int ii = 0; ii < 24; ++ii){
            float2 x[4], ww[6];
            #pragma unroll
            for (int j = 0; j < 4; ++j) x[j] = xS[(mg * 4 + j) * 24 + ii];
            #pragma unroll
            for (int t = 0; t < 6; ++t) ww[t] = wS[ii * 96 + og * 6 + t];
            #pragma unroll
            for (int j = 0; j < 4; ++j)
                #pragma unroll
                for (int t = 0; t < 6; ++t){
                    acc[j][t].x = fmaf(x[j].x, ww[t].x, fmaf(-x[j].y, ww[t].y, acc[j][t].x));
                    acc[j][t].y = fmaf(x[j].y, ww[t].x, fmaf( x[j].x, ww[t].y, acc[j][t].y));
                }
        }
    }

    const float* B0 = bias + blk * BSZ;
    const float* B1 = bias + (NBLK + blk) * BSZ;
    float* oR = outR + base;
    float* oI = outI + base;
    #pragma unroll
    for (int t = 0; t < 6; ++t){
        int o = og * 6 + t;
        float br = B0[o], bi = B1[o];
        #pragma unroll
        for (int j = 0; j < 4; ++j){
            float vr = acc[j][t].x + br;
            float vi = acc[j][t].y + bi;
            if (ACT == 1){ vr = fmaxf(vr, 0.f); vi = fmaxf(vi, 0.f); }
            else         { vr = softshrink01(vr); vi = softshrink01(vi); }
            size_t off = (size_t)(mg * 4 + j) * BSZ + o;
            oR[off] = vr;
            oI[off] = vi;
        }
    }
}

// ---------------- inverse rfft along W + skip-add ----------------
__global__ __launch_bounds__(256) void ifftW_kernel(
        const float* __restrict__ AR, const float* __restrict__ AI,
        float* __restrict__ mid, const float* __restrict__ iwT, int blk0)
{
    __shared__ float TR[WF * BSZ];
    __shared__ float TI[WF * BSZ];
    const int slot = blockIdx.y;
    const int blk = blk0 + slot;
    const int row2 = blockIdx.x;
    const float* srcR = AR + (size_t)slot * SZ_XW + (size_t)row2 * WF * BSZ;
    const float* srcI = AI + (size_t)slot * SZ_XW + (size_t)row2 * WF * BSZ;
    for (int idx = threadIdx.x; idx < WF * BSZ; idx += 256){
        TR[idx] = srcR[idx];
        TI[idx] = srcI[idx];
    }
    __syncthreads();
    float* dst = mid + (size_t)row2 * WWI * MED + blk * BSZ;
    const float2* tw2 = (const float2*)iwT;
    for (int idx = threadIdx.x; idx < WWI * BSZ; idx += 256){
        int w = idx / BSZ, c = idx - w * BSZ;
        const float2* t = tw2 + w * WF;
        float acc = 0.f;
        #pragma unroll 8
        for (int fq = 0; fq < WF; ++fq){
            float2 a = t[fq];
            acc = fmaf(TR[fq * BSZ + c], a.x, acc);
            acc = fmaf(TI[fq * BSZ + c], a.y, acc);
        }
        float* p = dst + (size_t)w * MED + c;
        *p = acc + *p;
    }
}

// ---------------- round-1 fused fallback (used only if ws too small) ----------------
__global__ __launch_bounds__(256) void fusedH_kernel(
        float* __restrict__ XwR, float* __restrict__ XwI,
        const float* __restrict__ w1, const float* __restrict__ b1,
        const float* __restrict__ w2, const float* __restrict__ b2,
        const float* __restrict__ hT, int blk)
{
    extern __shared__ float2 sm2[];
    float2* bufA = sm2;
    float2* bufB = sm2 + 5376;
    float2* wbuf = sm2 + 10752;
    const int tid = threadIdx.x;
    const int b = blockIdx.x / WF, f = blockIdx.x - b * WF;
    float* R = XwR + ((size_t)b * HH * WF + f) * BSZ;
    float* I = XwI + ((size_t)b * HH * WF + f) * BSZ;
    const float2* hTf = (const float2*)hT;
    const int HSTRIDE = WF * BSZ;

    for (int idx = tid; idx < HH * BSZ; idx += 256){
        int h = idx / BSZ, c = idx - h * BSZ;
        bufA[idx] = make_float2(R[(size_t)h * HSTRIDE + c], I[(size_t)h * HSTRIDE + c]);
    }
    __syncthreads();
    for (int idx = tid; idx < HH * BSZ; idx += 256){
        int k = idx / BSZ, c = idx - k * BSZ;
        const float2* tw = hTf + k * HH;
        float re = 0.f, im = 0.f;
        #pragma unroll 8
        for (int h = 0; h < HH; ++h){
            float2 t = bufA[h * BSZ + c];
            float2 w = tw[h];
            re += t.x * w.x + t.y * w.y;
            im += t.y * w.x - t.x * w.y;
        }
        bufB[idx] = make_float2(re, im);
    }
    const float* W10 = w1 + (size_t)blk * BSZ * BSZ;
    const float* W11 = w1 + (size_t)(NBLK + blk) * BSZ * BSZ;
    const float* B10 = b1 + blk * BSZ;
    const float* B11 = b1 + (NBLK + blk) * BSZ;
    #pragma unroll 1
    for (int half = 0; half < 2; ++half){
        const int base = half * 48;
        __syncthreads();
        for (int idx = tid; idx < BSZ * 48; idx += 256){
            int i = idx / 48, oo = idx - i * 48;
            wbuf[idx] = make_float2(W10[i * BSZ + base + oo], W11[i * BSZ + base + oo]);
        }
        __syncthreads();
        for (int t = tid; t < HH * 24; t += 256){
            int row = t / 24, oo = t - row * 24;
            int o = base + oo;
            float2 a0 = make_float2(B10[o],      B11[o]);
            float2 a1 = make_float2(B10[o + 24], B11[o + 24]);
            const float2* xr = bufB + row * BSZ;
            #pragma unroll 8
            for (int i = 0; i < BSZ; ++i){
                float2 x  = xr[i];
                float2 wa = wbuf[i * 48 + oo];
                float2 wb = wbuf[i * 48 + oo + 24];
                a0.x += x.x * wa.x - x.y * wa.y;
                a0.y += x.y * wa.x + x.x * wa.y;
                a1.x += x.x * wb.x - x.y * wb.y;
                a1.y += x.y * wb.x + x.x * wb.y;
            }
            bufA[row * BSZ + o]      = make_float2(fmaxf(a0.x, 0.f), fmaxf(a0.y, 0.f));
            bufA[row * BSZ + o + 24] = make_float2(fmaxf(a1.x, 0.f), fmaxf(a1.y, 0.f));
        }
    }
    const float* W20 = w2 + (size_t)blk * BSZ * BSZ;
    const float* W21 = w2 + (size_t)(NBLK + blk) * BSZ * BSZ;
    const float* B20 = b2 + blk * BSZ;
    const float* B21 = b2 + (NBLK + blk) * BSZ;
    #pragma unroll 1
    for (int half = 0; half < 2; ++half){
        const int base = half * 48;
        __syncthreads();
        for (int idx = tid; idx < BSZ * 48; idx += 256){
            int i = idx / 48, oo = idx - i * 48;
            wbuf[idx] = make_float2(W20[i * BSZ + base + oo], W21[i * BSZ + base + oo]);
        }
        __syncthreads();
        for (int t = tid; t < HH * 24; t += 256){
            int row = t / 24, oo = t - row * 24;
            int o = base + oo;
            float2 a0 = make_float2(B20[o],      B21[o]);
            float2 a1 = make_float2(B20[o + 24], B21[o + 24]);
            const float2* xr = bufA + row * BSZ;
            #pragma unroll 8
            for (int i = 0; i < BSZ; ++i){
                float2 x  = xr[i];
                float2 wa = wbuf[i * 48 + oo];
                float2 wb = wbuf[i * 48 + oo + 24];
                a0.x += x.x * wa.x - x.y * wa.y;
                a0.y += x.y * wa.x + x.x * wa.y;
                a1.x += x.x * wb.x - x.y * wb.y;
                a1.y += x.y * wb.x + x.x * wb.y;
            }
            bufB[row * BSZ + o]      = make_float2(softshrink01(a0.x), softshrink01(a0.y));
            bufB[row * BSZ + o + 24] = make_float2(softshrink01(a1.x), softshrink01(a1.y));
        }
    }
    __syncthreads();
    for (int idx = tid; idx < HH * BSZ; idx += 256){
        int h = idx / BSZ, c = idx - h * BSZ;
        const float2* tw = hTf + h * HH;
        float re = 0.f, im = 0.f;
        #pragma unroll 8
        for (int k = 0; k < HH; ++k){
            float2 t = bufB[k * BSZ + c];
            float2 w = tw[k];
            re += t.x * w.x - t.y * w.y;
            im += t.x * w.y + t.y * w.x;
        }
        R[(size_t)h * HSTRIDE + c] = re;
        I[(size_t)h * HSTRIDE + c] = im;
    }
}

// ---------------- launcher ----------------
extern "C" void kernel_launch(void* const* d_in, const int* in_sizes, int n_in,
                              void* d_out, int out_size, void* d_ws, size_t ws_size,
                              hipStream_t stream)
{
    (void)in_sizes; (void)n_in; (void)out_size;
    const float* x      = (const float*)d_in[0];
    const float* w_pw1  = (const float*)d_in[1];
    const float* sscale = (const float*)d_in[2];
    const float* sbias  = (const float*)d_in[3];
    const float* w1     = (const float*)d_in[4];
    const float* b1     = (const float*)d_in[5];
    const float* w2     = (const float*)d_in[6];
    const float* b2     = (const float*)d_in[7];
    const float* w_pw2  = (const float*)d_in[8];
    float* out = (float*)d_out;
    float* ws  = (float*)d_ws;

    const size_t bytes_old = (OFF_BUF + 2 * SZ_XW) * sizeof(float);   // ~348 MB
    const size_t bytes_n1  = (OFF_BUF + 4 * SZ_XW) * sizeof(float);   // ~388 MB
    const size_t bytes_n8  = (OFF_BUF + 32 * SZ_XW) * sizeof(float);  // ~947 MB

    int NY;
    bool newpath;
    if      (ws_size >= bytes_n8) { NY = 8; newpath = true; }
    else if (ws_size >= bytes_n1) { NY = 1; newpath = true; }
    else if (ws_size >= bytes_old){ NY = 1; newpath = false; }
    else return;

    float* cwF = ws + OFF_CWF;
    float* hTf = ws + OFF_HTF;
    float* hTi = ws + OFF_HTI;
    float* iwT = ws + OFF_IWT;
    float* mid = ws + OFF_MID;
    float* AR  = ws + OFF_BUF;
    float* AI  = AR + (size_t)NY * SZ_XW;
    float* BR  = AI + (size_t)NY * SZ_XW;
    float* BI  = BR + (size_t)NY * SZ_XW;

    init_tables_kernel<<<1, 256, 0, stream>>>(cwF, hTf, hTi, iwT);

    gemm_kernel<true><<<dim3(MROWS / 128, MED / 128), 256, 0, stream>>>(
        x, w_pw1, mid, CIN, MED, sscale, sbias);

    if (newpath){
        for (int blk0 = 0; blk0 < NBLK; blk0 += NY){
            dim3 gW(ROWS2, NY), gH(32 * 58, NY), gM(NPOS / 64, NY);
            fftW_kernel<<<gW, 256, 0, stream>>>(mid, AR, AI, cwF, blk0);
            cgemmH_kernel<<<gH, 256, 0, stream>>>(AR, AI, BR, BI, hTf);
            cmlp_kernel<1><<<gM, 256, 0, stream>>>(BR, BI, AR, AI, w1, b1, blk0);
            cmlp_kernel<2><<<gM, 256, 0, stream>>>(AR, AI, BR, BI, w2, b2, blk0);
            cgemmH_kernel<<<gH, 256, 0, stream>>>(BR, BI, AR, AI, hTi);
            ifftW_kernel<<<gW, 256, 0, stream>>>(AR, AI, mid, iwT, blk0);
        }
    } else {
        for (int blk = 0; blk < NBLK; ++blk){
            dim3 g1(ROWS2, 1);
            fftW_kernel<<<g1, 256, 0, stream>>>(mid, AR, AI, cwF, blk);
            fusedH_kernel<<<32 * WF, 256, 122880, stream>>>(AR, AI, w1, b1, w2, b2, hTi, blk);
            ifftW_kernel<<<g1, 256, 0, stream>>>(AR, AI, mid, iwT, blk);
        }
    }

    gemm_kernel<false><<<dim3(MROWS / 128, CIN / 128), 256, 0, stream>>>(
        mid, w_pw2, out, MED, CIN, nullptr, nullptr);
}

// Round 3
// 4865.147 us; speedup vs baseline: 1.9099x; 1.0180x over previous
//
#include <hip/hip_runtime.h>
#include <math.h>

#define TWO_PI_F 6.28318530717958647692f

// Problem constants: x [32,56,56,384], med=768, nb=8, bs=96, Wf=29
#define MROWS 100352      // 32*56*56
#define CIN   384
#define MED   768
#define NBLK  8
#define BSZ   96
#define HH    56
#define WWI   56
#define WF    29
#define ROWS2 1792        // 32*56
#define NPOS  51968       // ROWS2*WF (positions per channel-block)
#define NROW  2784        // WF*BSZ

#define SZ_XW ((size_t)ROWS2 * WF * BSZ)   // 4,988,928 floats per plane per slot
#define SZ_X  ((size_t)MROWS * CIN)        // 38,535,168
#define SZ_MIDE ((size_t)MROWS * MED)      // 77,070,336

// ---- ws layout (float offsets) ----
#define OFF_CWF 0
#define SZ_CWF  (WF*WWI*2)
#define OFF_HTF (OFF_CWF + SZ_CWF)
#define SZ_HT   (HH*HH*2)
#define OFF_HTI (OFF_HTF + SZ_HT)
#define OFF_IWT (OFF_HTI + SZ_HT)
#define SZ_IWT  (WWI*WF*2)
#define OFF_MID ((size_t)(OFF_IWT + SZ_IWT))   // 19040
#define OFF_A   (OFF_MID + SZ_MIDE)
#define PSLOT8  ((size_t)8 * SZ_XW)            // 39,911,424 floats per plane (NY=8)
// after planes: weight tables (new path only)
#define OFF_WMLP(ny) (OFF_A + (size_t)4*(size_t)(ny)*SZ_XW)
#define SZ_WMLP  (2*8*192*192/2)               // 294,912 floats (589,824 ushorts)
#define SZ_WT1   ((size_t)CIN*MED/2)           // 147,456 floats per table

static __device__ __forceinline__ float softshrink01(float v){
    float t = fabsf(v) - 0.01f;
    return (t > 0.f) ? copysignf(t, v) : 0.f;
}

typedef float f32x4 __attribute__((ext_vector_type(4)));
typedef __bf16 bf16x8v __attribute__((ext_vector_type(8)));
typedef unsigned short u16x8 __attribute__((ext_vector_type(8)));
typedef unsigned short u16x4 __attribute__((ext_vector_type(4)));

static __device__ __forceinline__ bf16x8v ld8(const unsigned short* p){
    return __builtin_bit_cast(bf16x8v, *(const u16x8*)p);
}
static __device__ __forceinline__ f32x4 MFMA(bf16x8v a, bf16x8v b, f32x4 c){
    return __builtin_amdgcn_mfma_f32_16x16x32_bf16(a, b, c, 0, 0, 0);
}
static __device__ __forceinline__ unsigned short bfbits(float f){
    __bf16 h = (__bf16)f;
    return __builtin_bit_cast(unsigned short, h);
}
static __device__ __forceinline__ bf16x8v cvtA8(const float* p){
    float4 u = *(const float4*)p;
    float4 v = *(const float4*)(p + 4);
    bf16x8v r;
    r[0]=(__bf16)u.x; r[1]=(__bf16)u.y; r[2]=(__bf16)u.z; r[3]=(__bf16)u.w;
    r[4]=(__bf16)v.x; r[5]=(__bf16)v.y; r[6]=(__bf16)v.z; r[7]=(__bf16)v.w;
    return r;
}

// ---------------- twiddle tables ----------------
__global__ __launch_bounds__(256) void init_tables_kernel(
        float* __restrict__ cwF, float* __restrict__ hTf,
        float* __restrict__ hTi, float* __restrict__ iwT)
{
    int tid = threadIdx.x;
    for (int idx = tid; idx < WF * WWI; idx += 256){
        int f = idx / WWI, w = idx % WWI;
        float ang = TWO_PI_F * (float)((f * w) % WWI) / (float)WWI;
        cwF[2*idx]   =  cosf(ang) * (1.f / 56.f);
        cwF[2*idx+1] = -sinf(ang) * (1.f / 56.f);
    }
    for (int idx = tid; idx < HH * HH; idx += 256){
        int k = idx / HH, h = idx % HH;
        float ang = TWO_PI_F * (float)((k * h) % HH) / (float)HH;
        float c = cosf(ang), s = sinf(ang);
        hTf[2*idx]   = c;  hTf[2*idx+1] = -s;
        hTi[2*idx]   = c;  hTi[2*idx+1] =  s;
    }
    for (int idx = tid; idx < WWI * WF; idx += 256){
        int w = idx / WF, f = idx % WF;
        float ang = TWO_PI_F * (float)((f * w) % WWI) / (float)WWI;
        float alpha = (f == 0 || f == WF - 1) ? 1.f : 2.f;
        iwT[2*idx]   =  alpha * cosf(ang) * (1.f / 56.f);
        iwT[2*idx+1] = -alpha * sinf(ang) * (1.f / 56.f);
    }
}

// ---------------- prep: fp32 -> bf16 hi/lo split planes ----------------
__global__ __launch_bounds__(256) void cvt_split_kernel(
        const float* __restrict__ src, unsigned short* __restrict__ hi,
        unsigned short* __restrict__ lo, size_t n4)
{
    size_t stride = (size_t)gridDim.x * 256;
    for (size_t i = blockIdx.x * 256 + threadIdx.x; i < n4; i += stride){
        float4 v = *(const float4*)(src + i * 4);
        u16x4 h, l;
        float f, hf;
        f = v.x; h[0] = bfbits(f); hf = (float)__builtin_bit_cast(__bf16, h[0]); l[0] = bfbits(f - hf);
        f = v.y; h[1] = bfbits(f); hf = (float)__builtin_bit_cast(__bf16, h[1]); l[1] = bfbits(f - hf);
        f = v.z; h[2] = bfbits(f); hf = (float)__builtin_bit_cast(__bf16, h[2]); l[2] = bfbits(f - hf);
        f = v.w; h[3] = bfbits(f); hf = (float)__builtin_bit_cast(__bf16, h[3]); l[3] = bfbits(f - hf);
        *(u16x4*)(hi + i * 4) = h;
        *(u16x4*)(lo + i * 4) = l;
    }
}

// ---------------- prep: weight transpose + split (tiny) ----------------
__global__ __launch_bounds__(256) void wT_split_kernel(
        const float* __restrict__ w, unsigned short* __restrict__ hi,
        unsigned short* __restrict__ lo, int K, int N)
{
    int total = K * N;
    for (int idx = blockIdx.x * 256 + threadIdx.x; idx < total; idx += gridDim.x * 256){
        int n = idx / K, k = idx - n * K;
        float f = w[(size_t)k * N + n];
        unsigned short h = bfbits(f);
        float hf = (float)__builtin_bit_cast(__bf16, h);
        hi[idx] = h;
        lo[idx] = bfbits(f - hf);
    }
}

// ---------------- prep: stacked-real MLP weight tables ----------------
// out[lay][blk][n 192][k 192] bf16:  n<96 real-out col o=n, n>=96 imag col o=n-96
__global__ __launch_bounds__(256) void wmlp_build_kernel(
        const float* __restrict__ w1, const float* __restrict__ w2,
        unsigned short* __restrict__ out)
{
    const int total = 2 * 8 * 192 * 192;
    for (int idx = blockIdx.x * 256 + threadIdx.x; idx < total; idx += gridDim.x * 256){
        int lay = idx / (8*192*192);
        int rem = idx - lay * (8*192*192);
        int blk = rem / (192*192);
        int rem2 = rem - blk * (192*192);
        int nn = rem2 / 192, k = rem2 - nn * 192;
        const float* W = lay ? w2 : w1;
        bool realn = nn < 96;
        int o = realn ? nn : nn - 96;
        float v;
        if (k < 96){
            v = realn ? W[((size_t)blk*96 + k)*96 + o]              //  W0[k][o]
                      : W[((size_t)(8+blk)*96 + k)*96 + o];          //  W1[k][o]
        } else {
            int i = k - 96;
            v = realn ? -W[((size_t)(8+blk)*96 + i)*96 + o]          // -W1[i][o]
                      :  W[((size_t)blk*96 + i)*96 + o];             //  W0[i][o]
        }
        out[idx] = bfbits(v);
    }
}

// ---------------- split-bf16 MFMA GEMM (pwconv1/pwconv2) ----------------
// C[M,N] = A[M,K]*B[K,N]; A given as hi/lo bf16 planes [M][K]; B as BT hi/lo [N][K].
// grid (M/128, N/128), 256 thr = 4 waves (2x2), wave = 64m x 64n.
#define GSPLIT_MFMA(FH, FL, GH, GL) \
    _Pragma("unroll") \
    for (int i = 0; i < 4; ++i){ \
        _Pragma("unroll") \
        for (int j = 0; j < 4; ++j){ \
            acc[i][j] = MFMA(FH[i], GH[j], acc[i][j]); \
            acc[i][j] = MFMA(FH[i], GL[j], acc[i][j]); \
            acc[i][j] = MFMA(FL[i], GH[j], acc[i][j]); \
        } \
    }

template<bool STAR>
__global__ __launch_bounds__(256) void gemm_mfma_kernel(
        const unsigned short* __restrict__ Ah, const unsigned short* __restrict__ Al,
        const unsigned short* __restrict__ Bh, const unsigned short* __restrict__ Bl,
        float* __restrict__ C, int Kd, int Nd,
        const float* __restrict__ sp, const float* __restrict__ bp)
{
    const int l = threadIdx.x & 63, wid = threadIdx.x >> 6;
    const int r = l & 15, g = l >> 4;
    const int mb = blockIdx.x * 128 + (wid >> 1) * 64;
    const int nb = blockIdx.y * 128 + (wid & 1) * 64;

    f32x4 acc[4][4];
    #pragma unroll
    for (int i = 0; i < 4; ++i)
        #pragma unroll
        for (int j = 0; j < 4; ++j)
            acc[i][j] = (f32x4){0.f, 0.f, 0.f, 0.f};

    size_t aoff[4], boff[4];
    #pragma unroll
    for (int i = 0; i < 4; ++i){
        aoff[i] = (size_t)(mb + i*16 + r) * Kd + 8*g;
        boff[i] = (size_t)(nb + i*16 + r) * Kd + 8*g;
    }

    bf16x8v a0h[4], a0l[4], b0h[4], b0l[4];
    bf16x8v a1h[4], a1l[4], b1h[4], b1l[4];
    #pragma unroll
    for (int i = 0; i < 4; ++i){
        a0h[i] = ld8(Ah + aoff[i]); a0l[i] = ld8(Al + aoff[i]);
        b0h[i] = ld8(Bh + boff[i]); b0l[i] = ld8(Bl + boff[i]);
    }

    for (int k0 = 0; k0 < Kd; k0 += 64){
        #pragma unroll
        for (int i = 0; i < 4; ++i){
            a1h[i] = ld8(Ah + aoff[i] + k0 + 32); a1l[i] = ld8(Al + aoff[i] + k0 + 32);
            b1h[i] = ld8(Bh + boff[i] + k0 + 32); b1l[i] = ld8(Bl + boff[i] + k0 + 32);
        }
        GSPLIT_MFMA(a0h, a0l, b0h, b0l)
        if (k0 + 64 < Kd){
            #pragma unroll
            for (int i = 0; i < 4; ++i){
                a0h[i] = ld8(Ah + aoff[i] + k0 + 64); a0l[i] = ld8(Al + aoff[i] + k0 + 64);
                b0h[i] = ld8(Bh + boff[i] + k0 + 64); b0l[i] = ld8(Bl + boff[i] + k0 + 64);
            }
        }
        GSPLIT_MFMA(a1h, a1l, b1h, b1l)
    }

    float s = 0.f, bb = 0.f;
    if (STAR){ s = sp[0]; bb = bp[0]; }
    #pragma unroll
    for (int i = 0; i < 4; ++i){
        #pragma unroll
        for (int j = 0; j < 4; ++j){
            #pragma unroll
            for (int q = 0; q < 4; ++q){
                int row = mb + i*16 + 4*g + q;
                int col = nb + j*16 + r;
                float v = acc[i][j][q];
                if (STAR){ float rr = fmaxf(v, 0.f); v = fmaf(s*rr, rr, bb); }
                C[(size_t)row * Nd + col] = v;
            }
        }
    }
}

// ---------------- bf16 MFMA block-diag complex MLP (stacked real) ----------------
// grid (NPOS/128 = 406, 8 slots); wave = 64m x 96n (n<96 real cols, else imag).
template<int ACT>
__global__ __launch_bounds__(256) void cmlp_mfma_kernel(
        const float* __restrict__ inR, const float* __restrict__ inI,
        float* __restrict__ outR, float* __restrict__ outI,
        const unsigned short* __restrict__ Wt, const float* __restrict__ bias)
{
    const int slot = blockIdx.y;
    const float* R = inR + (size_t)slot * SZ_XW;
    const float* I = inI + (size_t)slot * SZ_XW;
    float* oR = outR + (size_t)slot * SZ_XW;
    float* oI = outI + (size_t)slot * SZ_XW;
    const unsigned short* W = Wt + (size_t)slot * 192 * 192;

    const int l = threadIdx.x & 63, wid = threadIdx.x >> 6;
    const int r = l & 15, g = l >> 4;
    const int mb = blockIdx.x * 128 + (wid >> 1) * 64;
    const int nwv = (wid & 1) * 96;

    f32x4 acc[4][6];
    #pragma unroll
    for (int i = 0; i < 4; ++i)
        #pragma unroll
        for (int j = 0; j < 6; ++j)
            acc[i][j] = (f32x4){0.f, 0.f, 0.f, 0.f};

    size_t arow[4];
    #pragma unroll
    for (int i = 0; i < 4; ++i) arow[i] = (size_t)(mb + i*16 + r) * BSZ;
    size_t boff[6];
    #pragma unroll
    for (int j = 0; j < 6; ++j) boff[j] = (size_t)(nwv + j*16 + r) * 192 + 8*g;

    bf16x8v a0[4], b0[6], a1[4], b1[6];
    {
        const float* P = R;  // k0 = 0
        #pragma unroll
        for (int i = 0; i < 4; ++i) a0[i] = cvtA8(P + arow[i] + 8*g);
        #pragma unroll
        for (int j = 0; j < 6; ++j) b0[j] = ld8(W + boff[j]);
    }
    for (int k0 = 0; k0 < 192; k0 += 64){
        {
            int kk = k0 + 32;
            const float* P = (kk < 96) ? R : I;
            int c0 = (kk < 96) ? kk : kk - 96;
            #pragma unroll
            for (int i = 0; i < 4; ++i) a1[i] = cvtA8(P + arow[i] + c0 + 8*g);
            #pragma unroll
            for (int j = 0; j < 6; ++j) b1[j] = ld8(W + boff[j] + kk);
        }
        #pragma unroll
        for (int i = 0; i < 4; ++i)
            #pragma unroll
            for (int j = 0; j < 6; ++j)
                acc[i][j] = MFMA(a0[i], b0[j], acc[i][j]);
        if (k0 + 64 < 192){
            int kk = k0 + 64;
            const float* P = (kk < 96) ? R : I;
            int c0 = (kk < 96) ? kk : kk - 96;
            #pragma unroll
            for (int i = 0; i < 4; ++i) a0[i] = cvtA8(P + arow[i] + c0 + 8*g);
            #pragma unroll
            for (int j = 0; j < 6; ++j) b0[j] = ld8(W + boff[j] + kk);
        }
        #pragma unroll
        for (int i = 0; i < 4; ++i)
            #pragma unroll
            for (int j = 0; j < 6; ++j)
                acc[i][j] = MFMA(a1[i], b1[j], acc[i][j]);
    }

    #pragma unroll
    for (int j = 0; j < 6; ++j){
        int col = nwv + j*16 + r;
        bool realn = col < 96;
        int o = realn ? col : col - 96;
        float bv = realn ? bias[(size_t)slot * 96 + o]
                         : bias[(size_t)(8 + slot) * 96 + o];
        float* OP = realn ? oR : oI;
        #pragma unroll
        for (int i = 0; i < 4; ++i){
            #pragma unroll
            for (int q = 0; q < 4; ++q){
                int row = mb + i*16 + 4*g + q;
                float v = acc[i][j][q] + bv;
                if (ACT == 1) v = fmaxf(v, 0.f);
                else          v = softshrink01(v);
                OP[(size_t)row * BSZ + o] = v;
            }
        }
    }
}

// ---------------- fp32 GEMM (fallback only) ----------------
template<bool STAR>
__global__ __launch_bounds__(256) void gemm_kernel(
        const float* __restrict__ A, const float* __restrict__ B,
        float* __restrict__ C, int Kdim, int Ndim,
        const float* __restrict__ sptr, const float* __restrict__ bptr)
{
    __shared__ float As[16][132];
    __shared__ float Bs[16][128];
    const int tid = threadIdx.x;
    const int tx = tid & 15, ty = tid >> 4;
    const int bm = blockIdx.x, bn = blockIdx.y;

    float acc[8][8];
    #pragma unroll
    for (int i = 0; i < 8; ++i)
        #pragma unroll
        for (int j = 0; j < 8; ++j) acc[i][j] = 0.f;

    const float* Aptr = A + (size_t)bm * 128 * Kdim;
    const float* Bptr = B + (size_t)bn * 128;

    for (int k0 = 0; k0 < Kdim; k0 += 16){
        #pragma unroll
        for (int j = 0; j < 2; ++j){
            int m  = (tid >> 2) + j * 64;
            int kc = (tid & 3) * 4;
            const float4 va = *(const float4*)(Aptr + (size_t)m * Kdim + k0 + kc);
            As[kc+0][m] = va.x; As[kc+1][m] = va.y;
            As[kc+2][m] = va.z; As[kc+3][m] = va.w;
        }
        #pragma unroll
        for (int j = 0; j < 2; ++j){
            int kr = (tid >> 5) + j * 8;
            int nc = (tid & 31) * 4;
            *(float4*)(&Bs[kr][nc]) = *(const float4*)(Bptr + (size_t)(k0 + kr) * Ndim + nc);
        }
        __syncthreads();
        #pragma unroll
        for (int k = 0; k < 16; ++k){
            float a[8], b[8];
            *(float4*)(a)   = *(const float4*)(&As[k][ty*4]);
            *(float4*)(a+4) = *(const float4*)(&As[k][64 + ty*4]);
            *(float4*)(b)   = *(const float4*)(&Bs[k][tx*4]);
            *(float4*)(b+4) = *(const float4*)(&Bs[k][64 + tx*4]);
            #pragma unroll
            for (int i = 0; i < 8; ++i)
                #pragma unroll
                for (int j = 0; j < 8; ++j)
                    acc[i][j] = fmaf(a[i], b[j], acc[i][j]);
        }
        __syncthreads();
    }

    float s = 0.f, bb = 0.f;
    if (STAR){ s = sptr[0]; bb = bptr[0]; }
    #pragma unroll
    for (int i = 0; i < 8; ++i){
        int m = bm * 128 + ((i < 4) ? (ty*4 + i) : (64 + ty*4 + (i - 4)));
        #pragma unroll
        for (int jj = 0; jj < 2; ++jj){
            int n = bn * 128 + ((jj == 0) ? (tx*4) : (64 + tx*4));
            float4 v;
            v.x = acc[i][jj*4+0]; v.y = acc[i][jj*4+1];
            v.z = acc[i][jj*4+2]; v.w = acc[i][jj*4+3];
            if (STAR){
                float rr;
                rr = fmaxf(v.x, 0.f); v.x = fmaf(s*rr, rr, bb);
                rr = fmaxf(v.y, 0.f); v.y = fmaf(s*rr, rr, bb);
                rr = fmaxf(v.z, 0.f); v.z = fmaf(s*rr, rr, bb);
                rr = fmaxf(v.w, 0.f); v.w = fmaf(s*rr, rr, bb);
            }
            *(float4*)(&C[(size_t)m * Ndim + n]) = v;
        }
    }
}

// ---------------- forward rfft along W ----------------
__global__ __launch_bounds__(256) void fftW_kernel(
        const float* __restrict__ mid, float* __restrict__ AR, float* __restrict__ AI,
        const float* __restrict__ cwF, int blk0)
{
    __shared__ float T[WWI * BSZ];
    const int slot = blockIdx.y;
    const int blk = blk0 + slot;
    const int row2 = blockIdx.x;
    const float* src = mid + (size_t)row2 * WWI * MED + blk * BSZ;
    for (int idx = threadIdx.x; idx < WWI * BSZ; idx += 256){
        int w = idx / BSZ, c = idx - w * BSZ;
        T[idx] = src[(size_t)w * MED + c];
    }
    __syncthreads();
    float* dstR = AR + (size_t)slot * SZ_XW + (size_t)row2 * WF * BSZ;
    float* dstI = AI + (size_t)slot * SZ_XW + (size_t)row2 * WF * BSZ;
    const float2* tw2 = (const float2*)cwF;
    for (int idx = threadIdx.x; idx < WF * BSZ; idx += 256){
        int f = idx / BSZ, c = idx - f * BSZ;
        const float2* tw = tw2 + f * WWI;
        float re = 0.f, im = 0.f;
        #pragma unroll 8
        for (int w = 0; w < WWI; ++w){
            float v = T[w * BSZ + c];
            float2 t = tw[w];
            re = fmaf(v, t.x, re);
            im = fmaf(v, t.y, im);
        }
        dstR[idx] = re;
        dstI[idx] = im;
    }
}

// ---------------- complex DFT along H (fp32 register-tiled) ----------------
__global__ __launch_bounds__(256) void cgemmH_kernel(
        const float* __restrict__ inR, const float* __restrict__ inI,
        float* __restrict__ outR, float* __restrict__ outI,
        const float* __restrict__ twg)
{
    __shared__ float2 twS[HH * HH];
    __shared__ float2 bS[HH * 48];
    const int slot = blockIdx.y;
    const int b  = blockIdx.x / 58;
    const int n0 = (blockIdx.x - b * 58) * 48;
    const int tid = threadIdx.x;
    const size_t base = (size_t)slot * SZ_XW + (size_t)b * HH * NROW;
    const float* iR = inR + base;
    const float* iI = inI + base;

    const float2* twg2 = (const float2*)twg;
    for (int i = tid; i < HH * HH; i += 256) twS[i] = twg2[i];
    for (int i = tid; i < HH * 48; i += 256){
        int h = i / 48, n = i - h * 48;
        bS[i] = make_float2(iR[(size_t)h * NROW + n0 + n], iI[(size_t)h * NROW + n0 + n]);
    }
    __syncthreads();

    const int ng = tid & 15, kg = tid >> 4;
    if (kg < 14){
        float2 acc[4][3];
        #pragma unroll
        for (int j = 0; j < 4; ++j)
            #pragma unroll
            for (int t = 0; t < 3; ++t) acc[j][t] = make_float2(0.f, 0.f);

        for (int h = 0; h < HH; ++h){
            float2 x0 = bS[h * 48 + ng * 3 + 0];
            float2 x1 = bS[h * 48 + ng * 3 + 1];
            float2 x2 = bS[h * 48 + ng * 3 + 2];
            #pragma unroll
            for (int j = 0; j < 4; ++j){
                float2 w = twS[(kg * 4 + j) * HH + h];
                acc[j][0].x = fmaf(x0.x, w.x, fmaf(-x0.y, w.y, acc[j][0].x));
                acc[j][0].y = fmaf(x0.y, w.x, fmaf( x0.x, w.y, acc[j][0].y));
                acc[j][1].x = fmaf(x1.x, w.x, fmaf(-x1.y, w.y, acc[j][1].x));
                acc[j][1].y = fmaf(x1.y, w.x, fmaf( x1.x, w.y, acc[j][1].y));
                acc[j][2].x = fmaf(x2.x, w.x, fmaf(-x2.y, w.y, acc[j][2].x));
                acc[j][2].y = fmaf(x2.y, w.x, fmaf( x2.x, w.y, acc[j][2].y));
            }
        }
        float* oR = outR + base;
        float* oI = outI + base;
        #pragma unroll
        for (int j = 0; j < 4; ++j){
            int k = kg * 4 + j;
            #pragma unroll
            for (int t = 0; t < 3; ++t){
                int n = n0 + ng * 3 + t;
                oR[(size_t)k * NROW + n] = acc[j][t].x;
                oI[(size_t)k * NROW + n] = acc[j][t].y;
            }
        }
    }
}

// ---------------- fp32 block-diag complex MLP (fallback only) ----------------
template<int ACT>
__global__ __launch_bounds__(256) void cmlp_kernel(
        const float* __restrict__ inR, const float* __restrict__ inI,
        float* __restrict__ outR, float* __restrict__ outI,
        const float* __restrict__ w, const float* __restrict__ bias, int blk0)
{
    __shared__ float2 xS[64 * 24];
    __shared__ float2 wS[24 * 96];
    const int slot = blockIdx.y;
    const int blk = blk0 + slot;
    const int m0 = blockIdx.x * 64;
    const int tid = threadIdx.x;
    const float* W0 = w + (size_t)blk * BSZ * BSZ;
    const float* W1 = w + (size_t)(NBLK + blk) * BSZ * BSZ;
    const size_t base = (size_t)slot * SZ_XW + (size_t)m0 * BSZ;
    const float* iR = inR + base;
    const float* iI = inI + base;
    const int og = tid & 15, mg = tid >> 4;

    float2 acc[4][6];
    #pragma unroll
    for (int j = 0; j < 4; ++j)
        #pragma unroll
        for (int t = 0; t < 6; ++t) acc[j][t] = make_float2(0.f, 0.f);

    for (int i0 = 0; i0 < BSZ; i0 += 24){
        __syncthreads();
        for (int idx = tid; idx < 64 * 24; idx += 256){
            int m = idx / 24, ii = idx - m * 24;
            xS[idx] = make_float2(iR[(size_t)m * BSZ + i0 + ii], iI[(size_t)m * BSZ + i0 + ii]);
        }
        for (int idx = tid; idx < 24 * 96; idx += 256){
            int ii = idx / 96, o = idx - ii * 96;
            wS[idx] = make_float2(W0[(size_t)(i0 + ii) * BSZ + o], W1[(size_t)(i0 + ii) * BSZ + o]);
        }
        __syncthreads();
        for (int ii = 0; ii < 24; ++ii){
            float2 x[4], ww[6];
            #pragma unroll
            for (int j = 0; j < 4; ++j) x[j] = xS[(mg * 4 + j) * 24 + ii];
            #pragma unroll
            for (int t = 0; t < 6; ++t) ww[t] = wS[ii * 96 + og * 6 + t];
            #pragma unroll
            for (int j = 0; j < 4; ++j)
                #pragma unroll
                for (int t = 0; t < 6; ++t){
                    acc[j][t].x = fmaf(x[j].x, ww[t].x, fmaf(-x[j].y, ww[t].y, acc[j][t].x));
                    acc[j][t].y = fmaf(x[j].y, ww[t].x, fmaf( x[j].x, ww[t].y, acc[j][t].y));
                }
        }
    }

    const float* B0 = bias + blk * BSZ;
    const float* B1 = bias + (NBLK + blk) * BSZ;
    float* oR = outR + base;
    float* oI = outI + base;
    #pragma unroll
    for (int t = 0; t < 6; ++t){
        int o = og * 6 + t;
        float br = B0[o], bi = B1[o];
        #pragma unroll
        for (int j = 0; j < 4; ++j){
            float vr = acc[j][t].x + br;
            float vi = acc[j][t].y + bi;
            if (ACT == 1){ vr = fmaxf(vr, 0.f); vi = fmaxf(vi, 0.f); }
            else         { vr = softshrink01(vr); vi = softshrink01(vi); }
            size_t off = (size_t)(mg * 4 + j) * BSZ + o;
            oR[off] = vr;
            oI[off] = vi;
        }
    }
}

// ---------------- inverse rfft along W + skip-add ----------------
__global__ __launch_bounds__(256) void ifftW_kernel(
        const float* __restrict__ AR, const float* __restrict__ AI,
        float* __restrict__ mid, const float* __restrict__ iwT, int blk0)
{
    __shared__ float TR[WF * BSZ];
    __shared__ float TI[WF * BSZ];
    const int slot = blockIdx.y;
    const int blk = blk0 + slot;
    const int row2 = blockIdx.x;
    const float* srcR = AR + (size_t)slot * SZ_XW + (size_t)row2 * WF * BSZ;
    const float* srcI = AI + (size_t)slot * SZ_XW + (size_t)row2 * WF * BSZ;
    for (int idx = threadIdx.x; idx < WF * BSZ; idx += 256){
        TR[idx] = srcR[idx];
        TI[idx] = srcI[idx];
    }
    __syncthreads();
    float* dst = mid + (size_t)row2 * WWI * MED + blk * BSZ;
    const float2* tw2 = (const float2*)iwT;
    for (int idx = threadIdx.x; idx < WWI * BSZ; idx += 256){
        int w = idx / BSZ, c = idx - w * BSZ;
        const float2* t = tw2 + w * WF;
        float acc = 0.f;
        #pragma unroll 8
        for (int fq = 0; fq < WF; ++fq){
            float2 a = t[fq];
            acc = fmaf(TR[fq * BSZ + c], a.x, acc);
            acc = fmaf(TI[fq * BSZ + c], a.y, acc);
        }
        float* p = dst + (size_t)w * MED + c;
        *p = acc + *p;
    }
}

// ---------------- launcher ----------------
extern "C" void kernel_launch(void* const* d_in, const int* in_sizes, int n_in,
                              void* d_out, int out_size, void* d_ws, size_t ws_size,
                              hipStream_t stream)
{
    (void)in_sizes; (void)n_in; (void)out_size;
    const float* x      = (const float*)d_in[0];
    const float* w_pw1  = (const float*)d_in[1];
    const float* sscale = (const float*)d_in[2];
    const float* sbias  = (const float*)d_in[3];
    const float* w1     = (const float*)d_in[4];
    const float* b1     = (const float*)d_in[5];
    const float* w2     = (const float*)d_in[6];
    const float* b2     = (const float*)d_in[7];
    const float* w_pw2  = (const float*)d_in[8];
    float* out = (float*)d_out;
    float* ws  = (float*)d_ws;

    const size_t fp32_n8_floats = OFF_A + 4 * PSLOT8;
    const size_t new_floats     = fp32_n8_floats + SZ_WMLP + 4 * SZ_WT1;
    const size_t bytes_new      = new_floats * sizeof(float);
    const size_t bytes_f8       = fp32_n8_floats * sizeof(float);
    const size_t bytes_f1       = (OFF_A + 4 * SZ_XW) * sizeof(float);

    float* cwF = ws + OFF_CWF;
    float* hTf = ws + OFF_HTF;
    float* hTi = ws + OFF_HTI;
    float* iwT = ws + OFF_IWT;
    float* mid = ws + OFF_MID;

    init_tables_kernel<<<1, 256, 0, stream>>>(cwF, hTf, hTi, iwT);

    if (ws_size >= bytes_new){
        // ---- MFMA path, NY = 8 ----
        float* AR = ws + OFF_A;
        float* AI = AR + PSLOT8;
        float* BR = AI + PSLOT8;
        float* BI = BR + PSLOT8;
        unsigned short* wmlp = (unsigned short*)(ws + fp32_n8_floats);
        unsigned short* w1Th = (unsigned short*)(ws + fp32_n8_floats + SZ_WMLP);
        unsigned short* w1Tl = w1Th + (size_t)CIN * MED;
        unsigned short* w2Th = w1Tl + (size_t)CIN * MED;
        unsigned short* w2Tl = w2Th + (size_t)CIN * MED;
        // overlays (dead/live windows verified):
        unsigned short* xhi = (unsigned short*)BR;           // live: pwconv1 only
        unsigned short* xlo = xhi + SZ_X;
        unsigned short* mhi = (unsigned short*)BR;           // live: after spectral
        unsigned short* mlo = mhi + SZ_MIDE;

        cvt_split_kernel<<<2048, 256, 0, stream>>>(x, xhi, xlo, SZ_X / 4);
        wT_split_kernel<<<256, 256, 0, stream>>>(w_pw1, w1Th, w1Tl, CIN, MED);
        wT_split_kernel<<<256, 256, 0, stream>>>(w_pw2, w2Th, w2Tl, MED, CIN);
        wmlp_build_kernel<<<512, 256, 0, stream>>>(w1, w2, wmlp);

        gemm_mfma_kernel<true><<<dim3(MROWS/128, MED/128), 256, 0, stream>>>(
            xhi, xlo, w1Th, w1Tl, mid, CIN, MED, sscale, sbias);

        dim3 gW(ROWS2, 8), gH(32 * 58, 8), gM(NPOS / 128, 8);
        fftW_kernel<<<gW, 256, 0, stream>>>(mid, AR, AI, cwF, 0);
        cgemmH_kernel<<<gH, 256, 0, stream>>>(AR, AI, BR, BI, hTf);
        cmlp_mfma_kernel<1><<<gM, 256, 0, stream>>>(BR, BI, AR, AI, wmlp, b1);
        cmlp_mfma_kernel<2><<<gM, 256, 0, stream>>>(AR, AI, BR, BI, wmlp + (size_t)8*192*192, b2);
        cgemmH_kernel<<<gH, 256, 0, stream>>>(BR, BI, AR, AI, hTi);
        ifftW_kernel<<<gW, 256, 0, stream>>>(AR, AI, mid, iwT, 0);

        cvt_split_kernel<<<2048, 256, 0, stream>>>(mid, mhi, mlo, SZ_MIDE / 4);
        gemm_mfma_kernel<false><<<dim3(MROWS/128, CIN/128), 256, 0, stream>>>(
            mhi, mlo, w2Th, w2Tl, out, MED, CIN, nullptr, nullptr);
    } else if (ws_size >= bytes_f8 || ws_size >= bytes_f1){
        // ---- fp32 fallback ----
        int NY = (ws_size >= bytes_f8) ? 8 : 1;
        float* AR = ws + OFF_A;
        float* AI = AR + (size_t)NY * SZ_XW;
        float* BR = AI + (size_t)NY * SZ_XW;
        float* BI = BR + (size_t)NY * SZ_XW;

        gemm_kernel<true><<<dim3(MROWS/128, MED/128), 256, 0, stream>>>(
            x, w_pw1, mid, CIN, MED, sscale, sbias);
        for (int blk0 = 0; blk0 < NBLK; blk0 += NY){
            dim3 gW(ROWS2, NY), gH(32 * 58, NY), gM(NPOS / 64, NY);
            fftW_kernel<<<gW, 256, 0, stream>>>(mid, AR, AI, cwF, blk0);
            cgemmH_kernel<<<gH, 256, 0, stream>>>(AR, AI, BR, BI, hTf);
            cmlp_kernel<1><<<gM, 256, 0, stream>>>(BR, BI, AR, AI, w1, b1, blk0);
            cmlp_kernel<2><<<gM, 256, 0, stream>>>(AR, AI, BR, BI, w2, b2, blk0);
            cgemmH_kernel<<<gH, 256, 0, stream>>>(BR, BI, AR, AI, hTi);
            ifftW_kernel<<<gW, 256, 0, stream>>>(AR, AI, mid, iwT, blk0);
        }
        gemm_kernel<false><<<dim3(MROWS/128, CIN/128), 256, 0, stream>>>(
            mid, w_pw2, out, MED, CIN, nullptr, nullptr);
    }
}